// Round 10
// baseline (200.029 us; speedup 1.0000x reference)
//
#include <hip/hip_runtime.h>
#include <hip/hip_bf16.h>

typedef signed char i8;
typedef __attribute__((ext_vector_type(4))) int i32x4;
typedef __attribute__((ext_vector_type(4))) float f32x4;

typedef __attribute__((address_space(1))) void gvoid_t;
typedef __attribute__((address_space(3))) void lvoid_t;

#define S_QUANT (6.0f / 127.0f)
#define INV_S   (127.0f / 6.0f)

__device__ __forceinline__ void gload_lds16(const void* g, void* l) {
    __builtin_amdgcn_global_load_lds((gvoid_t*)g, (lvoid_t*)l, 16, 0, 0);
}

__device__ __forceinline__ i8 q8(float f) {
    return (i8)(int)rintf(fminf(fmaxf(f * INV_S, -127.f), 127.f));
}

__device__ __forceinline__ i8 sgn8(float v) {
    return v > 0.f ? (i8)1 : (v < 0.f ? (i8)-1 : (i8)0);
}

// ---------------- pre-pass 1: x (M*K fp32) -> i8 quantized ----------------
__global__ __launch_bounds__(256) void quant_x_kernel(const float* __restrict__ x,
                                                      i8* __restrict__ xq, long n16) {
    long i = (long)blockIdx.x * blockDim.x + threadIdx.x;
    if (i >= n16) return;
    const float4* p = (const float4*)(x + i * 16);
    union { i8 b[16]; i32x4 v; } o;
    #pragma unroll
    for (int j = 0; j < 4; j++) {
        float4 f = p[j];
        o.b[4 * j + 0] = q8(f.x);
        o.b[4 * j + 1] = q8(f.y);
        o.b[4 * j + 2] = q8(f.z);
        o.b[4 * j + 3] = q8(f.w);
    }
    *(i32x4*)(xq + i * 16) = o.v;
}

// ------ pre-pass 2: w (K x N fp32) -> Bt (N x K i8 of sign(w)) ------
__global__ __launch_bounds__(256) void binw_kernel(const float* __restrict__ w,
                                                   i8* __restrict__ bt,
                                                   int K, int N) {
    __shared__ i8 tile[64][68];   // +4 pad
    int n0 = blockIdx.x * 64;
    int k0 = blockIdx.y * 64;
    int t  = threadIdx.x;
    int cr = t >> 4;
    int cc = (t & 15) << 2;

    #pragma unroll
    for (int i = 0; i < 4; i++) {
        int r = cr + i * 16;
        float4 v = *(const float4*)(w + (long)(k0 + r) * N + n0 + cc);
        char4 s;
        s.x = sgn8(v.x); s.y = sgn8(v.y); s.z = sgn8(v.z); s.w = sgn8(v.w);
        *(char4*)&tile[r][cc] = s;
    }
    __syncthreads();
    #pragma unroll
    for (int i = 0; i < 4; i++) {
        int nl = cr + i * 16;
        char4 o;
        o.x = tile[cc + 0][nl];
        o.y = tile[cc + 1][nl];
        o.z = tile[cc + 2][nl];
        o.w = tile[cc + 3][nl];
        *(char4*)(bt + (long)(n0 + nl) * K + k0 + cc) = o;
    }
}

// ===== 256x256 8-phase i8 GEMM — R6 structure, bH (n=2,3) from GLOBAL =====
// C(MxN,f32) = s*|g| * Aq(MxK,i8) * Bt(NxK,i8)^T
// A/bL paths, staging, and the vmcnt ledger are UNCHANGED from the verified
// R6/R9 kernel. Only bH's 4 LDS reads/wave/buffer are replaced by 4 global
// loads issued at PH4/PH8 TAILS (1.5 phases before PH6/PH2 use). Global
// address derived symbolically from the verified LDS read (swizzle cancels):
//   Bt[(bcol + wc*64 + n*16 + (lane&15))*K + kk + (lane>>4)*16 (+64 for ks1)]
// Compiler tracks these C-level loads (and counts gload_lds in vmcnt), so
// its auto-inserted waits only drain B-staging EARLY — my PH3/PH7 vmcnt(2)
// still drain exactly buf.A halves (re-verified ledger).
// LDS reads/buffer: 192 KB -> 160 KB (-17%).

#define BARRIER() do{ __builtin_amdgcn_sched_barrier(0); __builtin_amdgcn_s_barrier(); __builtin_amdgcn_sched_barrier(0); }while(0)
#define SCHED0   __builtin_amdgcn_sched_barrier(0)
#define WAIT_LGKM(n) do{ asm volatile("s_waitcnt lgkmcnt(" #n ")" ::: "memory"); __builtin_amdgcn_sched_barrier(0); }while(0)

__global__ __launch_bounds__(512, 2) void gemm_bin8(const i8* __restrict__ A,
                                                    const i8* __restrict__ Bt,
                                                    const float* __restrict__ gp,
                                                    float* __restrict__ C,
                                                    int M, int N, int K) {
    __shared__ __align__(16) char lds[131072];

    int nwg = gridDim.x;
    int bid = blockIdx.x;
    int swz = ((nwg & 7) == 0) ? ((bid & 7) * (nwg >> 3) + (bid >> 3)) : bid;
    int tiles_n = N >> 8;
    int tm = swz / tiles_n;
    int tn = swz - tm * tiles_n;
    long brow = (long)tm << 8;
    long bcol = (long)tn << 8;

    const int tid  = threadIdx.x;
    const int lane = tid & 63;
    const int wid  = tid >> 6;
    const int wr = wid >> 2;     // 0..1
    const int wc = wid & 3;      // 0..3

    // ---- staging source pointers (inverse-swizzled global BYTE addresses) ----
    const int srow = tid >> 3;                               // 0..63
    const int scol = ((tid & 7) ^ ((tid >> 3) & 7)) << 4;    // bytes (16 i8)
    const i8* aSrc[4];
    const i8* bSrc[4];
    #pragma unroll
    for (int q = 0; q < 4; q++) {
        aSrc[q] = A  + (brow + q * 64 + srow) * (long)K + scol;
        bSrc[q] = Bt + (bcol + q * 64 + srow) * (long)K + scol;
    }
    char* dAB = lds + tid * 16;            // + b*32768 + h*16384 + j*8192
    char* dBB = lds + 65536 + tid * 16;

#define ST_A(b,h,kg) do{ \
    gload_lds16(aSrc[2*(h)]   + (kg), dAB + (b)*32768 + (h)*16384); \
    gload_lds16(aSrc[2*(h)+1] + (kg), dAB + (b)*32768 + (h)*16384 + 8192); }while(0)
#define ST_B(b,h,kg) do{ \
    gload_lds16(bSrc[2*(h)]   + (kg), dBB + (b)*32768 + (h)*16384); \
    gload_lds16(bSrc[2*(h)+1] + (kg), dBB + (b)*32768 + (h)*16384 + 8192); }while(0)

    // ---- fragment ds_read byte addresses (swizzled) ----
    const int swzc = (lane & 7) << 4;
    const int c0 = (((lane >> 4) << 4)) ^ swzc;        // ks0: k-bytes 0-63
    const int c1 = (64 | ((lane >> 4) << 4)) ^ swzc;   // ks1: k-bytes 64-127
    const char* Ab = lds + wr * 16384 + (lane & 15) * 128;
    const char* Bb = lds + 65536 + (wc >> 1) * 16384 + ((wc & 1) * 64 + (lane & 15)) * 128;

#define LDA(b,m,ks) (*(const i32x4*)(Ab + (b)*32768 + (m)*2048 + ((ks)?c1:c0)))
#define LDB(b,n,ks) (*(const i32x4*)(Bb + (b)*32768 + (n)*2048 + ((ks)?c1:c0)))

#define RD_A4_KS(B_, MB, KS) do{ _Pragma("unroll") for (int m_=0;m_<4;++m_){ a4[m_][KS]=LDA(B_,(MB)+m_,KS);} }while(0)
#define RD_B2(B_, NB, BF) do{ _Pragma("unroll") for (int n_=0;n_<2;++n_){ BF[n_][0]=LDB(B_,(NB)+n_,0); BF[n_][1]=LDB(B_,(NB)+n_,1);} }while(0)

    // ---- bH global base: row = bcol + wc*64 + 32 + (lane&15), k-slot (lane>>4)*16
    const i8* bpH = Bt + (bcol + wc * 64 + 32 + (lane & 15)) * (long)K
                       + ((lane >> 4) << 4);
    const long rowK16 = (long)K << 4;    // 16 rows stride

// load bH (n=2,3) for k-base kk straight from global (compiler-gated)
#define HGLOAD(kk) do{ \
    bH[0][0] = *(const i32x4*)(bpH + (kk)); \
    bH[0][1] = *(const i32x4*)(bpH + (kk) + 64); \
    bH[1][0] = *(const i32x4*)(bpH + rowK16 + (kk)); \
    bH[1][1] = *(const i32x4*)(bpH + rowK16 + (kk) + 64); \
    __builtin_amdgcn_sched_barrier(0); }while(0)

// half-QUAD: 8 MFMA, one ks slice (K=64 each)
#define HQUAD(MB, NB, BF, KS) do{ \
    __builtin_amdgcn_s_setprio(1); \
    _Pragma("unroll") \
    for (int m_ = 0; m_ < 4; ++m_) { \
        _Pragma("unroll") \
        for (int n_ = 0; n_ < 2; ++n_) { \
            acc[(MB)+m_][(NB)+n_] = __builtin_amdgcn_mfma_i32_16x16x64_i8(a4[m_][KS], BF[n_][KS], acc[(MB)+m_][(NB)+n_], 0, 0, 0); \
        } } \
    __builtin_amdgcn_s_setprio(0); \
}while(0)

    i32x4 acc[8][4];
    #pragma unroll
    for (int m = 0; m < 8; m++)
        #pragma unroll
        for (int n = 0; n < 4; n++)
            acc[m][n] = (i32x4){0, 0, 0, 0};

    i32x4 a4[4][2], bL[2][2], bH[2][2];

    // ---- prologue: buf0 full (k 0-127), buf1.B (k 128-255) ----
    ST_A(0, 0, 0); ST_A(0, 1, 0); ST_B(0, 0, 0); ST_B(0, 1, 0);
    ST_B(1, 0, 128); ST_B(1, 1, 128);
    asm volatile("s_waitcnt vmcnt(4)" ::: "memory");
    BARRIER();
    RD_B2(0, 0, bL);     // ahead-read for PH1 (LDS)
    HGLOAD(0);           // bH(buf0) from global for PH2/PH4

    const int NIT = K >> 8;    // 2 buffers x K=128 per iteration
    for (int it = 0; it < NIT; ++it) {
        const long k1 = (long)(2 * it + 1) << 7;
        long k2 = (long)(2 * it + 2) << 7; if (k2 > K - 128) k2 = K - 128;
        long k3 = (long)(2 * it + 3) << 7; if (k3 > K - 128) k3 = K - 128;
        const long hk = (it + 1 < NIT) ? ((long)(it + 1) << 8) : 0;  // next buf0 k (dead on last)

        // ---- PH1: A(m0-3,b0) ks-split; Q00
        WAIT_LGKM(0);                    // bL ready
        RD_A4_KS(0, 0, 0); SCHED0;
        RD_A4_KS(0, 0, 1);
        ST_A(1, 0, k1);
        WAIT_LGKM(4);                    // ks0 landed
        HQUAD(0, 0, bL, 0);
        WAIT_LGKM(0);                    // ks1 landed
        HQUAD(0, 0, bL, 1);
        BARRIER();

        // ---- PH2: Q01 (bH from global, compiler-gated)
        WAIT_LGKM(0);
        ST_A(1, 1, k1);
        SCHED0;
        HQUAD(0, 2, bH, 0);
        HQUAD(0, 2, bH, 1);
        BARRIER();

        // ---- PH3: A(m4-7,b0) ks-split; Q10; publish buf1@k1 (A halves)
        RD_A4_KS(0, 4, 0); SCHED0;
        RD_A4_KS(0, 4, 1);
        ST_B(0, 0, k2);
        WAIT_LGKM(4);
        HQUAD(4, 0, bL, 0);
        WAIT_LGKM(0);
        HQUAD(4, 0, bL, 1);
        asm volatile("s_waitcnt vmcnt(2)" ::: "memory");
        BARRIER();

        // ---- PH4: bL(b1) ahead (buf1 published); Q11; tail: bH(b1)@k1 global
        RD_B2(1, 0, bL);
        ST_B(0, 1, k2);
        SCHED0;
        HQUAD(4, 2, bH, 0);
        HQUAD(4, 2, bH, 1);
        SCHED0;
        HGLOAD(k1);
        BARRIER();

        // ---- PH5: A(m0-3,b1) ks-split; Q00
        WAIT_LGKM(0);
        RD_A4_KS(1, 0, 0); SCHED0;
        RD_A4_KS(1, 0, 1);
        ST_A(0, 0, k2);
        WAIT_LGKM(4);
        HQUAD(0, 0, bL, 0);
        WAIT_LGKM(0);
        HQUAD(0, 0, bL, 1);
        BARRIER();

        // ---- PH6: Q01
        WAIT_LGKM(0);
        ST_A(0, 1, k2);
        SCHED0;
        HQUAD(0, 2, bH, 0);
        HQUAD(0, 2, bH, 1);
        BARRIER();

        // ---- PH7: A(m4-7,b1) ks-split; Q10; publish buf0@k2 (A halves)
        RD_A4_KS(1, 4, 0); SCHED0;
        RD_A4_KS(1, 4, 1);
        ST_B(1, 0, k3);
        WAIT_LGKM(4);
        HQUAD(4, 0, bL, 0);
        WAIT_LGKM(0);
        HQUAD(4, 0, bL, 1);
        asm volatile("s_waitcnt vmcnt(2)" ::: "memory");
        BARRIER();

        // ---- PH8: bL(b0@k2) ahead; Q11; tail: bH(next buf0)@hk global
        RD_B2(0, 0, bL);
        ST_B(1, 1, k3);
        SCHED0;
        HQUAD(4, 2, bH, 0);
        HQUAD(4, 2, bH, 1);
        SCHED0;
        HGLOAD(hk);
        BARRIER();
    }

    asm volatile("s_waitcnt vmcnt(0) lgkmcnt(0)" ::: "memory");

    // ---- epilogue: scale i32 acc -> f32, vectorized NT stores via LDS ----
    float g = fabsf(gp[0]) * S_QUANT;
    float* Cs = (float*)lds;
    const int e_row = wr * 16 + ((lane >> 4) << 2);   // + j
    const int e_col = wc * 64 + (lane & 15);          // + n*16
    const int rrow  = tid >> 6;                       // 0..7
    const int rcol  = (tid & 63) << 2;                // 0..252
    #pragma unroll
    for (int m = 0; m < 8; m++) {
        if (m) BARRIER();          // previous readback done before overwrite
        #pragma unroll
        for (int n = 0; n < 4; n++)
            #pragma unroll
            for (int j = 0; j < 4; j++)
                Cs[(e_row + j) * 260 + e_col + n * 16] = g * (float)acc[m][n][j];
        BARRIER();
        #pragma unroll
        for (int rep = 0; rep < 4; rep++) {
            int lr = rrow + rep * 8;                  // 0..31
            f32x4 v = *(const f32x4*)(Cs + lr * 260 + rcol);
            long grow = brow + (long)(lr >> 4) * 128 + m * 16 + (lr & 15);
            __builtin_nontemporal_store(v, (f32x4*)(C + grow * (long)N + bcol + rcol));
        }
    }
}

// ---------------- fallback: naive fp32 ----------------
__global__ void fb_gemm(const float* __restrict__ x, const float* __restrict__ w,
                        const float* __restrict__ gp, float* __restrict__ out,
                        int M, int N, int K) {
    __shared__ float xs[16][17];
    __shared__ float ws[16][17];
    int tx = threadIdx.x, ty = threadIdx.y;
    long row = (long)blockIdx.y * 16 + ty;
    long col = (long)blockIdx.x * 16 + tx;
    float s = 0.f;
    for (int k0 = 0; k0 < K; k0 += 16) {
        xs[ty][tx] = x[row * K + k0 + tx];
        float wv = w[(long)(k0 + ty) * N + col];
        ws[ty][tx] = wv > 0.f ? 1.f : (wv < 0.f ? -1.f : 0.f);
        __syncthreads();
        #pragma unroll
        for (int kk = 0; kk < 16; kk++) s += xs[ty][kk] * ws[kk][tx];
        __syncthreads();
    }
    out[row * N + col] = fabsf(gp[0]) * s;
}

extern "C" void kernel_launch(void* const* d_in, const int* in_sizes, int n_in,
                              void* d_out, int out_size, void* d_ws, size_t ws_size,
                              hipStream_t stream) {
    const float* x  = (const float*)d_in[0];
    const float* w  = (const float*)d_in[1];
    const float* gp = (const float*)d_in[2];
    float* out = (float*)d_out;

    const int K = 4096, N = 4096;
    const int M = in_sizes[0] / K;   // 8192

    size_t need = (size_t)M * K + (size_t)N * K;   // 48 MiB (i8)
    bool shape_ok = (M % 256 == 0) && (N % 256 == 0) && (K % 256 == 0);
    if (ws_size >= need && shape_ok) {
        i8* xq = (i8*)d_ws;
        i8* bt = xq + (size_t)M * K;

        long n16 = (long)M * K / 16;
        quant_x_kernel<<<(int)((n16 + 255) / 256), 256, 0, stream>>>(x, xq, n16);

        dim3 gt(N / 64, K / 64);
        binw_kernel<<<gt, 256, 0, stream>>>(w, bt, K, N);

        int grid = (M / 256) * (N / 256);   // 512
        gemm_bin8<<<grid, 512, 0, stream>>>(xq, bt, gp, out, M, N, K);
    } else {
        dim3 g(N / 16, M / 16), b(16, 16);
        fb_gemm<<<g, b, 0, stream>>>(x, w, gp, out, M, N, K);
    }
}

// Round 11
// 150.683 us; speedup vs baseline: 1.3275x; 1.3275x over previous
//
#include <hip/hip_runtime.h>
#include <hip/hip_bf16.h>

typedef signed char i8;
typedef __attribute__((ext_vector_type(4))) int i32x4;
typedef __attribute__((ext_vector_type(4))) float f32x4;

typedef __attribute__((address_space(1))) void gvoid_t;
typedef __attribute__((address_space(3))) void lvoid_t;

#define S_QUANT (6.0f / 127.0f)
#define INV_S   (127.0f / 6.0f)

__device__ __forceinline__ void gload_lds16(const void* g, void* l) {
    __builtin_amdgcn_global_load_lds((gvoid_t*)g, (lvoid_t*)l, 16, 0, 0);
}

__device__ __forceinline__ i8 q8(float f) {
    return (i8)(int)rintf(fminf(fmaxf(f * INV_S, -127.f), 127.f));
}

__device__ __forceinline__ i8 sgn8(float v) {
    return v > 0.f ? (i8)1 : (v < 0.f ? (i8)-1 : (i8)0);
}

// ---------------- pre-pass 1: x (M*K fp32) -> i8 quantized (R6, plain loads) ----------------
__global__ __launch_bounds__(256) void quant_x_kernel(const float* __restrict__ x,
                                                      i8* __restrict__ xq, long n16) {
    long i = (long)blockIdx.x * blockDim.x + threadIdx.x;
    if (i >= n16) return;
    const float4* p = (const float4*)(x + i * 16);
    union { i8 b[16]; i32x4 v; } o;
    #pragma unroll
    for (int j = 0; j < 4; j++) {
        float4 f = p[j];
        o.b[4 * j + 0] = q8(f.x);
        o.b[4 * j + 1] = q8(f.y);
        o.b[4 * j + 2] = q8(f.z);
        o.b[4 * j + 3] = q8(f.w);
    }
    *(i32x4*)(xq + i * 16) = o.v;
}

// ------ pre-pass 2: w (K x N fp32) -> Bt (N x K i8 of sign(w)) (R6, plain loads) ------
__global__ __launch_bounds__(256) void binw_kernel(const float* __restrict__ w,
                                                   i8* __restrict__ bt,
                                                   int K, int N) {
    __shared__ i8 tile[64][68];   // +4 pad
    int n0 = blockIdx.x * 64;
    int k0 = blockIdx.y * 64;
    int t  = threadIdx.x;
    int cr = t >> 4;
    int cc = (t & 15) << 2;

    #pragma unroll
    for (int i = 0; i < 4; i++) {
        int r = cr + i * 16;
        float4 v = *(const float4*)(w + (long)(k0 + r) * N + n0 + cc);
        char4 s;
        s.x = sgn8(v.x); s.y = sgn8(v.y); s.z = sgn8(v.z); s.w = sgn8(v.w);
        *(char4*)&tile[r][cc] = s;
    }
    __syncthreads();
    #pragma unroll
    for (int i = 0; i < 4; i++) {
        int nl = cr + i * 16;
        char4 o;
        o.x = tile[cc + 0][nl];
        o.y = tile[cc + 1][nl];
        o.z = tile[cc + 2][nl];
        o.w = tile[cc + 3][nl];
        *(char4*)(bt + (long)(n0 + nl) * K + k0 + cc) = o;
    }
}

// ================= 256x256 8-phase i8 GEMM (verified R6 structure + NT C-stores) =================
// C(MxN,f32) = s*|g| * Aq(MxK,i8) * Bt(NxK,i8)^T
// 8 waves (2M x 4N), buffer covers K=128 i8 (2 x 64-k subtiles = ks0/ks1),
// 2 buffers/iter -> K=256 per iteration, NIT = K/256.
// LDS 128KB, T2 swizzle byte ^= ((row&7)<<4); gload_lds staging with
// inverse-swizzled global source; counted vmcnt(4)/vmcnt(2) publishes;
// B-frags read one phase ahead (WAR-safe, zero extra regs); A-frags
// ks-split (issue 8, lgkm(4), 8 MFMA, lgkm(0), 8 MFMA).
// NT C-stores in epilogue (C is write-once streaming; keeps A/Bt in L2).

#define BARRIER() do{ __builtin_amdgcn_sched_barrier(0); __builtin_amdgcn_s_barrier(); __builtin_amdgcn_sched_barrier(0); }while(0)
#define SCHED0   __builtin_amdgcn_sched_barrier(0)
#define WAIT_LGKM(n) do{ asm volatile("s_waitcnt lgkmcnt(" #n ")" ::: "memory"); __builtin_amdgcn_sched_barrier(0); }while(0)

__global__ __launch_bounds__(512, 2) void gemm_bin8(const i8* __restrict__ A,
                                                    const i8* __restrict__ Bt,
                                                    const float* __restrict__ gp,
                                                    float* __restrict__ C,
                                                    int M, int N, int K) {
    __shared__ __align__(16) char lds[131072];

    int nwg = gridDim.x;
    int bid = blockIdx.x;
    int swz = ((nwg & 7) == 0) ? ((bid & 7) * (nwg >> 3) + (bid >> 3)) : bid;
    int tiles_n = N >> 8;
    int tm = swz / tiles_n;
    int tn = swz - tm * tiles_n;
    long brow = (long)tm << 8;
    long bcol = (long)tn << 8;

    const int tid  = threadIdx.x;
    const int lane = tid & 63;
    const int wid  = tid >> 6;
    const int wr = wid >> 2;     // 0..1
    const int wc = wid & 3;      // 0..3

    // ---- staging source pointers (inverse-swizzled global BYTE addresses) ----
    const int srow = tid >> 3;                               // 0..63
    const int scol = ((tid & 7) ^ ((tid >> 3) & 7)) << 4;    // bytes (16 i8)
    const i8* aSrc[4];
    const i8* bSrc[4];
    #pragma unroll
    for (int q = 0; q < 4; q++) {
        aSrc[q] = A  + (brow + q * 64 + srow) * (long)K + scol;
        bSrc[q] = Bt + (bcol + q * 64 + srow) * (long)K + scol;
    }
    char* dAB = lds + tid * 16;            // + b*32768 + h*16384 + j*8192
    char* dBB = lds + 65536 + tid * 16;

#define ST_A(b,h,kg) do{ \
    gload_lds16(aSrc[2*(h)]   + (kg), dAB + (b)*32768 + (h)*16384); \
    gload_lds16(aSrc[2*(h)+1] + (kg), dAB + (b)*32768 + (h)*16384 + 8192); }while(0)
#define ST_B(b,h,kg) do{ \
    gload_lds16(bSrc[2*(h)]   + (kg), dBB + (b)*32768 + (h)*16384); \
    gload_lds16(bSrc[2*(h)+1] + (kg), dBB + (b)*32768 + (h)*16384 + 8192); }while(0)

    // ---- fragment ds_read byte addresses (swizzled) ----
    const int swzc = (lane & 7) << 4;
    const int c0 = (((lane >> 4) << 4)) ^ swzc;        // ks0: k-bytes 0-63
    const int c1 = (64 | ((lane >> 4) << 4)) ^ swzc;   // ks1: k-bytes 64-127
    const char* Ab = lds + wr * 16384 + (lane & 15) * 128;
    const char* Bb = lds + 65536 + (wc >> 1) * 16384 + ((wc & 1) * 64 + (lane & 15)) * 128;

#define LDA(b,m,ks) (*(const i32x4*)(Ab + (b)*32768 + (m)*2048 + ((ks)?c1:c0)))
#define LDB(b,n,ks) (*(const i32x4*)(Bb + (b)*32768 + (n)*2048 + ((ks)?c1:c0)))

#define RD_A4_KS(B_, MB, KS) do{ _Pragma("unroll") for (int m_=0;m_<4;++m_){ a4[m_][KS]=LDA(B_,(MB)+m_,KS);} }while(0)
#define RD_B2(B_, NB, BF) do{ _Pragma("unroll") for (int n_=0;n_<2;++n_){ BF[n_][0]=LDB(B_,(NB)+n_,0); BF[n_][1]=LDB(B_,(NB)+n_,1);} }while(0)

// half-QUAD: 8 MFMA, one ks slice (K=64 each)
#define HQUAD(MB, NB, BF, KS) do{ \
    __builtin_amdgcn_s_setprio(1); \
    _Pragma("unroll") \
    for (int m_ = 0; m_ < 4; ++m_) { \
        _Pragma("unroll") \
        for (int n_ = 0; n_ < 2; ++n_) { \
            acc[(MB)+m_][(NB)+n_] = __builtin_amdgcn_mfma_i32_16x16x64_i8(a4[m_][KS], BF[n_][KS], acc[(MB)+m_][(NB)+n_], 0, 0, 0); \
        } } \
    __builtin_amdgcn_s_setprio(0); \
}while(0)

    i32x4 acc[8][4];
    #pragma unroll
    for (int m = 0; m < 8; m++)
        #pragma unroll
        for (int n = 0; n < 4; n++)
            acc[m][n] = (i32x4){0, 0, 0, 0};

    i32x4 a4[4][2], bL[2][2], bH[2][2];

    // ---- prologue: buf0 full (k 0-127), buf1.B (k 128-255) ----
    ST_A(0, 0, 0); ST_A(0, 1, 0); ST_B(0, 0, 0); ST_B(0, 1, 0);
    ST_B(1, 0, 128); ST_B(1, 1, 128);
    asm volatile("s_waitcnt vmcnt(4)" ::: "memory");
    BARRIER();
    RD_B2(0, 0, bL);     // ahead-read for PH1

    const int NIT = K >> 8;    // 2 buffers x K=128 per iteration
    for (int it = 0; it < NIT; ++it) {
        const long k1 = (long)(2 * it + 1) << 7;
        long k2 = (long)(2 * it + 2) << 7; if (k2 > K - 128) k2 = K - 128;
        long k3 = (long)(2 * it + 3) << 7; if (k3 > K - 128) k3 = K - 128;

        // ---- PH1: A(m0-3,b0) ks-split; bH(b0) ahead; Q00
        WAIT_LGKM(0);                    // bL ready
        RD_A4_KS(0, 0, 0); SCHED0;
        RD_A4_KS(0, 0, 1);
        ST_A(1, 0, k1);
        WAIT_LGKM(4);                    // ks0 landed
        RD_B2(0, 2, bH); SCHED0;         // ahead for PH2
        HQUAD(0, 0, bL, 0);
        WAIT_LGKM(4);                    // ks1 landed (bH still out)
        HQUAD(0, 0, bL, 1);
        BARRIER();

        // ---- PH2: Q01
        WAIT_LGKM(0);
        ST_A(1, 1, k1);
        SCHED0;
        HQUAD(0, 2, bH, 0);
        HQUAD(0, 2, bH, 1);
        BARRIER();

        // ---- PH3: A(m4-7,b0) ks-split; Q10; publish buf1@k1
        RD_A4_KS(0, 4, 0); SCHED0;
        RD_A4_KS(0, 4, 1);
        ST_B(0, 0, k2);
        WAIT_LGKM(4);
        HQUAD(4, 0, bL, 0);
        WAIT_LGKM(0);
        HQUAD(4, 0, bL, 1);
        asm volatile("s_waitcnt vmcnt(2)" ::: "memory");
        BARRIER();

        // ---- PH4: bL(b1) ahead (buf1 published); Q11
        RD_B2(1, 0, bL);
        ST_B(0, 1, k2);
        SCHED0;
        HQUAD(4, 2, bH, 0);
        HQUAD(4, 2, bH, 1);
        BARRIER();

        // ---- PH5: A(m0-3,b1) ks-split; bH(b1) ahead; Q00
        WAIT_LGKM(0);
        RD_A4_KS(1, 0, 0); SCHED0;
        RD_A4_KS(1, 0, 1);
        ST_A(0, 0, k2);
        WAIT_LGKM(4);
        RD_B2(1, 2, bH); SCHED0;
        HQUAD(0, 0, bL, 0);
        WAIT_LGKM(4);
        HQUAD(0, 0, bL, 1);
        BARRIER();

        // ---- PH6: Q01
        WAIT_LGKM(0);
        ST_A(0, 1, k2);
        SCHED0;
        HQUAD(0, 2, bH, 0);
        HQUAD(0, 2, bH, 1);
        BARRIER();

        // ---- PH7: A(m4-7,b1) ks-split; Q10; publish buf0@k2
        RD_A4_KS(1, 4, 0); SCHED0;
        RD_A4_KS(1, 4, 1);
        ST_B(1, 0, k3);
        WAIT_LGKM(4);
        HQUAD(4, 0, bL, 0);
        WAIT_LGKM(0);
        HQUAD(4, 0, bL, 1);
        asm volatile("s_waitcnt vmcnt(2)" ::: "memory");
        BARRIER();

        // ---- PH8: bL(b0@k2) ahead for next iter; Q11
        RD_B2(0, 0, bL);
        ST_B(1, 1, k3);
        SCHED0;
        HQUAD(4, 2, bH, 0);
        HQUAD(4, 2, bH, 1);
        BARRIER();
    }

    asm volatile("s_waitcnt vmcnt(0) lgkmcnt(0)" ::: "memory");

    // ---- epilogue: scale i32 acc -> f32, vectorized NT stores via LDS ----
    float g = fabsf(gp[0]) * S_QUANT;
    float* Cs = (float*)lds;
    const int e_row = wr * 16 + ((lane >> 4) << 2);   // + j
    const int e_col = wc * 64 + (lane & 15);          // + n*16
    const int rrow  = tid >> 6;                       // 0..7
    const int rcol  = (tid & 63) << 2;                // 0..252
    #pragma unroll
    for (int m = 0; m < 8; m++) {
        if (m) BARRIER();          // previous readback done before overwrite
        #pragma unroll
        for (int n = 0; n < 4; n++)
            #pragma unroll
            for (int j = 0; j < 4; j++)
                Cs[(e_row + j) * 260 + e_col + n * 16] = g * (float)acc[m][n][j];
        BARRIER();
        #pragma unroll
        for (int rep = 0; rep < 4; rep++) {
            int lr = rrow + rep * 8;                  // 0..31
            f32x4 v = *(const f32x4*)(Cs + lr * 260 + rcol);
            long grow = brow + (long)(lr >> 4) * 128 + m * 16 + (lr & 15);
            __builtin_nontemporal_store(v, (f32x4*)(C + grow * (long)N + bcol + rcol));
        }
    }
}

// ---------------- fallback: naive fp32 ----------------
__global__ void fb_gemm(const float* __restrict__ x, const float* __restrict__ w,
                        const float* __restrict__ gp, float* __restrict__ out,
                        int M, int N, int K) {
    __shared__ float xs[16][17];
    __shared__ float ws[16][17];
    int tx = threadIdx.x, ty = threadIdx.y;
    long row = (long)blockIdx.y * 16 + ty;
    long col = (long)blockIdx.x * 16 + tx;
    float s = 0.f;
    for (int k0 = 0; k0 < K; k0 += 16) {
        xs[ty][tx] = x[row * K + k0 + tx];
        float wv = w[(long)(k0 + ty) * N + col];
        ws[ty][tx] = wv > 0.f ? 1.f : (wv < 0.f ? -1.f : 0.f);
        __syncthreads();
        #pragma unroll
        for (int kk = 0; kk < 16; kk++) s += xs[ty][kk] * ws[kk][tx];
        __syncthreads();
    }
    out[row * N + col] = fabsf(gp[0]) * s;
}

extern "C" void kernel_launch(void* const* d_in, const int* in_sizes, int n_in,
                              void* d_out, int out_size, void* d_ws, size_t ws_size,
                              hipStream_t stream) {
    const float* x  = (const float*)d_in[0];
    const float* w  = (const float*)d_in[1];
    const float* gp = (const float*)d_in[2];
    float* out = (float*)d_out;

    const int K = 4096, N = 4096;
    const int M = in_sizes[0] / K;   // 8192

    size_t need = (size_t)M * K + (size_t)N * K;   // 48 MiB (i8)
    bool shape_ok = (M % 256 == 0) && (N % 256 == 0) && (K % 256 == 0);
    if (ws_size >= need && shape_ok) {
        i8* xq = (i8*)d_ws;
        i8* bt = xq + (size_t)M * K;

        long n16 = (long)M * K / 16;
        quant_x_kernel<<<(int)((n16 + 255) / 256), 256, 0, stream>>>(x, xq, n16);

        dim3 gt(N / 64, K / 64);
        binw_kernel<<<gt, 256, 0, stream>>>(w, bt, K, N);

        int grid = (M / 256) * (N / 256);   // 512
        gemm_bin8<<<grid, 512, 0, stream>>>(xq, bt, gp, out, M, N, K);
    } else {
        dim3 g(N / 16, M / 16), b(16, 16);
        fb_gemm<<<g, b, 0, stream>>>(x, w, gp, out, M, N, K);
    }
}